// Round 1
// baseline (423.913 us; speedup 1.0000x reference)
//
#include <hip/hip_runtime.h>

// RNN: h_t = tanh(x_t * W_ih^T + b_ih + h_{t-1} W_hh^T + b_hh), out = h_T W_fc^T + b_fc
// B=8192, T=784, I=1, H=30 (pad 32), C=10. fp32.
//
// R3 design: same 16-threads-per-batch / 2-rows-per-thread decomposition as R2,
// but the per-step h broadcast now goes through the VALU DPP crossbar
// (v_mov_b32 row_newbcast:k, 4 independent 16-lane rows per wave = 4 batches)
// instead of LDS. R2 was LDS-return-BW-bound: 8 waves/CU x 8 ds_read_b128 x
// 8clk = 512 clk/CU-step (~49 TB/s, 70% of LDS ceiling). DPP movs are plain
// VALU (2 clk each), so the DS pipe drops out of the main loop entirely.
// Weights are packed as float2 so the MAC loop can select v_pk_fma_f32
// (packed fp32 = full-rate on gfx950; scalar fmac is half rate).

#define BB 8192
#define TT 784
#define HH 30
#define CC 10
#define NB 16      // batches per 256-thread block (4 per wave)
#define LSTR 36    // LDS row stride (floats) for the final FC exchange

typedef __attribute__((ext_vector_type(2))) float f32x2;

// broadcast lane k (within each 16-lane DPP row) of v to all lanes of the row
#define BC(v, k) __uint_as_float((unsigned)__builtin_amdgcn_update_dpp( \
        0, (int)__float_as_uint(v), 0x150 | (k), 0xF, 0xF, false))

#define KSTEP(k, P0, P1) {            \
        f32x2 hh;                     \
        hh.x = BC(h0, k);             \
        hh.y = BC(h1, k);             \
        P0 += w0[k] * hh;             \
        P1 += w1[k] * hh; }

__global__ __launch_bounds__(256, 2)
void rnn_scan_kernel(const float* __restrict__ x,
                     const float* __restrict__ W_ih,
                     const float* __restrict__ W_hh,
                     const float* __restrict__ b_ih,
                     const float* __restrict__ b_hh,
                     const float* __restrict__ W_fc,
                     const float* __restrict__ b_fc,
                     float* __restrict__ out) {
    __shared__ float hbuf[NB * LSTR];

    const int tid = threadIdx.x;
    const int bl  = tid >> 4;          // local batch 0..15 (4 per wave)
    const int r   = tid & 15;          // row-group 0..15 == DPP row lane
    const int i0  = r * 2;             // owned rows i0, i0+1
    const int b   = blockIdx.x * NB + bl;

    // --- per-thread weights: rows i0,i0+1 packed as float2 column pairs ---
    f32x2 w0[16], w1[16];
    const bool v0 = (i0 < HH), v1 = (i0 + 1 < HH);
#pragma unroll
    for (int k = 0; k < 16; ++k) {
        const int c0 = 2 * k, c1 = 2 * k + 1;
        w0[k].x = (v0 && c0 < HH) ? W_hh[i0 * HH + c0] : 0.0f;
        w0[k].y = (v0 && c1 < HH) ? W_hh[i0 * HH + c1] : 0.0f;
        w1[k].x = (v1 && c0 < HH) ? W_hh[(i0 + 1) * HH + c0] : 0.0f;
        w1[k].y = (v1 && c1 < HH) ? W_hh[(i0 + 1) * HH + c1] : 0.0f;
    }
    const float bias0 = v0 ? (b_ih[i0] + b_hh[i0]) : 0.0f;
    const float bias1 = v1 ? (b_ih[i0 + 1] + b_hh[i0 + 1]) : 0.0f;
    const float wih0  = v0 ? W_ih[i0] : 0.0f;
    const float wih1  = v1 ? W_ih[i0 + 1] : 0.0f;

    // h lives entirely in registers: lane r holds h[2r], h[2r+1].
    // invalid rows (r=15) stay exactly 0: acc==0 -> tanh->1-2*rcp(2)==0.
    float h0 = 0.0f, h1 = 0.0f;

    const float* xb = x + (size_t)b * TT;
    float4 xq = *(const float4*)(xb);

    for (int q = 0; q < TT / 4; ++q) {
        float4 nxt = (q + 1 < TT / 4) ? *(const float4*)(xb + (q + 1) * 4)
                                      : make_float4(0.f, 0.f, 0.f, 0.f);
#pragma unroll
        for (int u = 0; u < 4; ++u) {
            const float xt = (u == 0) ? xq.x : (u == 1) ? xq.y
                           : (u == 2) ? xq.z : xq.w;
            const float base0 = bias0 + xt * wih0;
            const float base1 = bias1 + xt * wih1;
            // 4 packed accumulators -> dep chains of 8 pk_fmas
            f32x2 p0a = {0.f, 0.f}, p0b = {0.f, 0.f};
            f32x2 p1a = {0.f, 0.f}, p1b = {0.f, 0.f};
            KSTEP( 0, p0a, p1a) KSTEP( 1, p0b, p1b)
            KSTEP( 2, p0a, p1a) KSTEP( 3, p0b, p1b)
            KSTEP( 4, p0a, p1a) KSTEP( 5, p0b, p1b)
            KSTEP( 6, p0a, p1a) KSTEP( 7, p0b, p1b)
            KSTEP( 8, p0a, p1a) KSTEP( 9, p0b, p1b)
            KSTEP(10, p0a, p1a) KSTEP(11, p0b, p1b)
            KSTEP(12, p0a, p1a) KSTEP(13, p0b, p1b)
            KSTEP(14, p0a, p1a) KSTEP(15, p0b, p1b)
            const f32x2 s0 = p0a + p0b;
            const f32x2 s1 = p1a + p1b;
            const float acc0 = base0 + s0.x + s0.y;
            const float acc1 = base1 + s1.x + s1.y;
            // tanh(a) = 1 - 2/(e^{2a}+1)
            h0 = 1.0f - 2.0f * __builtin_amdgcn_rcpf(__expf(2.0f * acc0) + 1.0f);
            h1 = 1.0f - 2.0f * __builtin_amdgcn_rcpf(__expf(2.0f * acc1) + 1.0f);
        }
        xq = nxt;
    }

    // --- FC head: park final h in LDS once; threads r<10 each do one output.
    // DS pipe is in-order per wave, wave_barrier keeps program order.
    float* hp = &hbuf[bl * LSTR];
    *(float2*)&hp[i0] = make_float2(h0, h1);
    __builtin_amdgcn_wave_barrier();

    if (r < CC) {
        const int c = r;
        float acc = b_fc[c];
#pragma unroll
        for (int j = 0; j < HH; ++j)
            acc += W_fc[c * HH + j] * hp[j];
        out[(size_t)b * CC + c] = acc;
    }
}

extern "C" void kernel_launch(void* const* d_in, const int* in_sizes, int n_in,
                              void* d_out, int out_size, void* d_ws, size_t ws_size,
                              hipStream_t stream) {
    const float* x    = (const float*)d_in[0];
    const float* W_ih = (const float*)d_in[1];
    const float* W_hh = (const float*)d_in[2];
    const float* b_ih = (const float*)d_in[3];
    const float* b_hh = (const float*)d_in[4];
    const float* W_fc = (const float*)d_in[5];
    const float* b_fc = (const float*)d_in[6];

    hipLaunchKernelGGL(rnn_scan_kernel,
                       dim3(BB / NB), dim3(NB * 16), 0, stream,
                       x, W_ih, W_hh, b_ih, b_hh, W_fc, b_fc,
                       (float*)d_out);
}

// Round 2
// 346.247 us; speedup vs baseline: 1.2243x; 1.2243x over previous
//
#include <hip/hip_runtime.h>

// RNN: h_t = tanh(x_t * W_ih^T + b_ih + h_{t-1} W_hh^T + b_hh), out = h_T W_fc^T + b_fc
// B=8192, T=784, I=1, H=30 (pad 32), C=10. fp32.
//
// R4 design: 16 threads/batch, 2 rows/thread (as R2/R3), but the h broadcast
// is FUSED into the MAC: v_fmac_f32_dpp acc, h, w row_newbcast:k (inline asm).
// R3's update_dpp route cost ~8 clk/broadcast (tied-old v_mov + DPP hazard
// s_nops => 256 instr/step measured). fmac_dpp does broadcast+MAC in ONE
// 2-clk VOP2: 64 fmacs/step = the scalar-FMA floor for this decomposition.
// No LDS in the main loop (R2's 512 clk/CU-step DS floor is gone too).
// All MAC asms are volatile to pin the 4-way interleaved chain order
// (8-cyc dep spacing > 4-cyc FMA latency); s_nop 1 at step head covers the
// VALU-write -> DPP-read hazard on h0/h1 (hazard recognizer can't see into
// inline asm). row_newbcast semantics verified on silicon by R3 (passed).

#define BB 8192
#define TT 784
#define HH 30
#define CC 10
#define NB 16      // batches per 256-thread block (4 per wave)
#define LSTR 36    // LDS row stride (floats) for the final FC exchange

// acc += w * broadcast(h from lane k of the 16-lane DPP row)
#define FMAC_BC(acc, h, w, k) \
    asm volatile("v_fmac_f32_dpp %0, %1, %2 row_newbcast:" #k \
                 " row_mask:0xf bank_mask:0xf" \
                 : "+v"(acc) : "v"(h), "v"(w))

// dst = w * broadcast(h from lane k)   (chain head, saves the zero-init mov)
#define MUL_BC(dst, h, w, k) \
    asm volatile("v_mul_f32_dpp %0, %1, %2 row_newbcast:" #k \
                 " row_mask:0xf bank_mask:0xf" \
                 : "=v"(dst) : "v"(h), "v"(w))

#define STEP4(k) \
    FMAC_BC(a0,  h0, w0c[2*(k)],   k); \
    FMAC_BC(a0b, h1, w0c[2*(k)+1], k); \
    FMAC_BC(a1,  h0, w1c[2*(k)],   k); \
    FMAC_BC(a1b, h1, w1c[2*(k)+1], k);

__global__ __launch_bounds__(256, 2)
void rnn_scan_kernel(const float* __restrict__ x,
                     const float* __restrict__ W_ih,
                     const float* __restrict__ W_hh,
                     const float* __restrict__ b_ih,
                     const float* __restrict__ b_hh,
                     const float* __restrict__ W_fc,
                     const float* __restrict__ b_fc,
                     float* __restrict__ out) {
    __shared__ float hbuf[NB * LSTR];

    const int tid = threadIdx.x;
    const int bl  = tid >> 4;          // local batch 0..15 (4 per wave)
    const int r   = tid & 15;          // lane within the 16-lane DPP row
    const int i0  = r * 2;             // owned rows i0, i0+1
    const int b   = blockIdx.x * NB + bl;

    // --- per-thread weights: rows i0, i0+1, zero-padded to 32 cols ---
    float w0c[32], w1c[32];
    const bool v0 = (i0 < HH), v1 = (i0 + 1 < HH);
#pragma unroll
    for (int j = 0; j < 32; ++j) {
        w0c[j] = (v0 && j < HH) ? W_hh[i0 * HH + j] : 0.0f;
        w1c[j] = (v1 && j < HH) ? W_hh[(i0 + 1) * HH + j] : 0.0f;
    }
    const float bias0 = v0 ? (b_ih[i0] + b_hh[i0]) : 0.0f;
    const float bias1 = v1 ? (b_ih[i0 + 1] + b_hh[i0 + 1]) : 0.0f;
    const float wih0  = v0 ? W_ih[i0] : 0.0f;
    const float wih1  = v1 ? W_ih[i0 + 1] : 0.0f;

    // h lives entirely in registers: lane r holds h[2r], h[2r+1].
    // invalid rows (r=15): acc==0 -> h = 1 - 2*rcp(2) == 0 exactly.
    float h0 = 0.0f, h1 = 0.0f;

    const float* xb = x + (size_t)b * TT;
    float4 xq = *(const float4*)(xb);

    for (int q = 0; q < TT / 4; ++q) {
        float4 nxt = (q + 1 < TT / 4) ? *(const float4*)(xb + (q + 1) * 4)
                                      : make_float4(0.f, 0.f, 0.f, 0.f);
#pragma unroll
        for (int u = 0; u < 4; ++u) {
            const float xt = (u == 0) ? xq.x : (u == 1) ? xq.y
                           : (u == 2) ? xq.z : xq.w;
            float a0 = fmaf(xt, wih0, bias0);
            float a1 = fmaf(xt, wih1, bias1);
            float a0b, a1b;
            // cover VALU-write(h0/h1) -> DPP-read hazard (2 wait states)
            asm volatile("s_nop 1");
            // k=0 group: b-chains start with MUL (no zero-init needed)
            FMAC_BC(a0,  h0, w0c[0], 0);
            MUL_BC (a0b, h1, w0c[1], 0);
            FMAC_BC(a1,  h0, w1c[0], 0);
            MUL_BC (a1b, h1, w1c[1], 0);
            STEP4( 1) STEP4( 2) STEP4( 3) STEP4( 4) STEP4( 5)
            STEP4( 6) STEP4( 7) STEP4( 8) STEP4( 9) STEP4(10)
            STEP4(11) STEP4(12) STEP4(13) STEP4(14) STEP4(15)
            const float acc0 = a0 + a0b;
            const float acc1 = a1 + a1b;
            // tanh(a) = 1 - 2/(e^{2a}+1)   (identical numerics to R2/R3)
            h0 = 1.0f - 2.0f * __builtin_amdgcn_rcpf(__expf(2.0f * acc0) + 1.0f);
            h1 = 1.0f - 2.0f * __builtin_amdgcn_rcpf(__expf(2.0f * acc1) + 1.0f);
        }
        xq = nxt;
    }

    // --- FC head: park final h in LDS once; threads r<10 each do one output.
    float* hp = &hbuf[bl * LSTR];
    *(float2*)&hp[i0] = make_float2(h0, h1);
    __builtin_amdgcn_wave_barrier();

    if (r < CC) {
        const int c = r;
        float acc = b_fc[c];
#pragma unroll
        for (int j = 0; j < HH; ++j)
            acc += W_fc[c * HH + j] * hp[j];
        out[(size_t)b * CC + c] = acc;
    }
}

extern "C" void kernel_launch(void* const* d_in, const int* in_sizes, int n_in,
                              void* d_out, int out_size, void* d_ws, size_t ws_size,
                              hipStream_t stream) {
    const float* x    = (const float*)d_in[0];
    const float* W_ih = (const float*)d_in[1];
    const float* W_hh = (const float*)d_in[2];
    const float* b_ih = (const float*)d_in[3];
    const float* b_hh = (const float*)d_in[4];
    const float* W_fc = (const float*)d_in[5];
    const float* b_fc = (const float*)d_in[6];

    hipLaunchKernelGGL(rnn_scan_kernel,
                       dim3(BB / NB), dim3(NB * 16), 0, stream,
                       x, W_ih, W_hh, b_ih, b_hh, W_fc, b_fc,
                       (float*)d_out);
}

// Round 3
// 338.231 us; speedup vs baseline: 1.2533x; 1.0237x over previous
//
#include <hip/hip_runtime.h>

// RNN: h_t = tanh(x_t * W_ih^T + b_ih + h_{t-1} W_hh^T + b_hh), out = h_T W_fc^T + b_fc
// B=8192, T=784, I=1, H=30 (pad 32), C=10. fp32.
//
// R5 = R4 (fmac_dpp broadcast-fused MACs) + REGISTER-PINNED weights.
// R4 post-mortem: VGPR_Count=44 proved the 64 per-lane weight floats were
// NOT register-resident -- the allocator rematerialized the global loads
// inside the hot loop (~60 L1-hit VMEM loads + waits per step, ~300 extra
// clk/wave-step). Fix: opaque empty-asm pin per element; an asm output
// cannot be rematerialized, so the weights stay in VGPRs for the whole
// kernel. launch_bounds(256,2) leaves 256 VGPRs/wave available.
// Also: columns 30,31 are structurally zero (w==0 AND h[30]=h[31]==0),
// so the k=15 DPP group is dropped: 60 MAC instrs/step.
//
// Expected floor: 60 fmac (120clk) + tanh tail (~45clk) + misc ~= 175
// clk/wave-step, 2 waves/SIMD -> ~350 clk/SIMD-step -> ~115 us.

#define BB 8192
#define TT 784
#define HH 30
#define CC 10
#define NB 16      // batches per 256-thread block (4 per wave)
#define LSTR 36    // LDS row stride (floats) for the final FC exchange

// acc += w * broadcast(h from lane k of the 16-lane DPP row)
#define FMAC_BC(acc, h, w, k) \
    asm volatile("v_fmac_f32_dpp %0, %1, %2 row_newbcast:" #k \
                 " row_mask:0xf bank_mask:0xf" \
                 : "+v"(acc) : "v"(h), "v"(w))

// dst = w * broadcast(h from lane k)   (chain head, saves the zero-init mov)
#define MUL_BC(dst, h, w, k) \
    asm volatile("v_mul_f32_dpp %0, %1, %2 row_newbcast:" #k \
                 " row_mask:0xf bank_mask:0xf" \
                 : "=v"(dst) : "v"(h), "v"(w))

#define STEP4(k) \
    FMAC_BC(a0,  h0, w0c[2*(k)],   k); \
    FMAC_BC(a0b, h1, w0c[2*(k)+1], k); \
    FMAC_BC(a1,  h0, w1c[2*(k)],   k); \
    FMAC_BC(a1b, h1, w1c[2*(k)+1], k);

__global__ __launch_bounds__(256, 2)
void rnn_scan_kernel(const float* __restrict__ x,
                     const float* __restrict__ W_ih,
                     const float* __restrict__ W_hh,
                     const float* __restrict__ b_ih,
                     const float* __restrict__ b_hh,
                     const float* __restrict__ W_fc,
                     const float* __restrict__ b_fc,
                     float* __restrict__ out) {
    __shared__ float hbuf[NB * LSTR];

    const int tid = threadIdx.x;
    const int bl  = tid >> 4;          // local batch 0..15 (4 per wave)
    const int r   = tid & 15;          // lane within the 16-lane DPP row
    const int i0  = r * 2;             // owned rows i0, i0+1
    const int b   = blockIdx.x * NB + bl;

    // --- per-thread weights: rows i0, i0+1, zero-padded to 32 cols ---
    float w0c[32], w1c[32];
    const bool v0 = (i0 < HH), v1 = (i0 + 1 < HH);
#pragma unroll
    for (int j = 0; j < 32; ++j) {
        w0c[j] = (v0 && j < HH) ? W_hh[i0 * HH + j] : 0.0f;
        w1c[j] = (v1 && j < HH) ? W_hh[(i0 + 1) * HH + j] : 0.0f;
    }
    float bias0 = v0 ? (b_ih[i0] + b_hh[i0]) : 0.0f;
    float bias1 = v1 ? (b_ih[i0 + 1] + b_hh[i0 + 1]) : 0.0f;
    float wih0  = v0 ? W_ih[i0] : 0.0f;
    float wih1  = v1 ? W_ih[i0 + 1] : 0.0f;

    // PIN everything loop-invariant into VGPRs: an asm output cannot be
    // rematerialized, so the allocator must keep these resident (the whole
    // point -- R4 re-loaded them from global every step).
#pragma unroll
    for (int j = 0; j < 32; ++j) {
        asm("" : "+v"(w0c[j]));
        asm("" : "+v"(w1c[j]));
    }
    asm("" : "+v"(bias0));
    asm("" : "+v"(bias1));
    asm("" : "+v"(wih0));
    asm("" : "+v"(wih1));

    // h lives entirely in registers: lane r holds h[2r], h[2r+1].
    // invalid rows (r=15): acc==0 -> h = 1 - 2*rcp(2) == 0 exactly.
    float h0 = 0.0f, h1 = 0.0f;

    const float* xb = x + (size_t)b * TT;
    float4 xq = *(const float4*)(xb);

    for (int q = 0; q < TT / 4; ++q) {
        float4 nxt = (q + 1 < TT / 4) ? *(const float4*)(xb + (q + 1) * 4)
                                      : make_float4(0.f, 0.f, 0.f, 0.f);
#pragma unroll
        for (int u = 0; u < 4; ++u) {
            const float xt = (u == 0) ? xq.x : (u == 1) ? xq.y
                           : (u == 2) ? xq.z : xq.w;
            float a0 = fmaf(xt, wih0, bias0);
            float a1 = fmaf(xt, wih1, bias1);
            float a0b, a1b;
            // cover VALU-write(h0/h1) -> DPP-read hazard (2 wait states)
            asm volatile("s_nop 1");
            // k=0 group: b-chains start with MUL (no zero-init needed)
            FMAC_BC(a0,  h0, w0c[0], 0);
            MUL_BC (a0b, h1, w0c[1], 0);
            FMAC_BC(a1,  h0, w1c[0], 0);
            MUL_BC (a1b, h1, w1c[1], 0);
            STEP4( 1) STEP4( 2) STEP4( 3) STEP4( 4) STEP4( 5)
            STEP4( 6) STEP4( 7) STEP4( 8) STEP4( 9) STEP4(10)
            STEP4(11) STEP4(12) STEP4(13) STEP4(14)
            // k=15 dropped: cols 30,31 have w==0 and h==0 (structural zeros)
            const float acc0 = a0 + a0b;
            const float acc1 = a1 + a1b;
            // tanh(a) = 1 - 2/(e^{2a}+1)   (identical numerics to R2..R4)
            h0 = 1.0f - 2.0f * __builtin_amdgcn_rcpf(__expf(2.0f * acc0) + 1.0f);
            h1 = 1.0f - 2.0f * __builtin_amdgcn_rcpf(__expf(2.0f * acc1) + 1.0f);
        }
        xq = nxt;
    }

    // --- FC head: park final h in LDS once; threads r<10 each do one output.
    float* hp = &hbuf[bl * LSTR];
    *(float2*)&hp[i0] = make_float2(h0, h1);
    __builtin_amdgcn_wave_barrier();

    if (r < CC) {
        const int c = r;
        float acc = b_fc[c];
#pragma unroll
        for (int j = 0; j < HH; ++j)
            acc += W_fc[c * HH + j] * hp[j];
        out[(size_t)b * CC + c] = acc;
    }
}

extern "C" void kernel_launch(void* const* d_in, const int* in_sizes, int n_in,
                              void* d_out, int out_size, void* d_ws, size_t ws_size,
                              hipStream_t stream) {
    const float* x    = (const float*)d_in[0];
    const float* W_ih = (const float*)d_in[1];
    const float* W_hh = (const float*)d_in[2];
    const float* b_ih = (const float*)d_in[3];
    const float* b_hh = (const float*)d_in[4];
    const float* W_fc = (const float*)d_in[5];
    const float* b_fc = (const float*)d_in[6];

    hipLaunchKernelGGL(rnn_scan_kernel,
                       dim3(BB / NB), dim3(NB * 16), 0, stream,
                       x, W_ih, W_hh, b_ih, b_hh, W_fc, b_fc,
                       (float*)d_out);
}

// Round 4
// 337.074 us; speedup vs baseline: 1.2576x; 1.0034x over previous
//
#include <hip/hip_runtime.h>

// RNN: h_t = tanh(x_t * W_ih^T + b_ih + h_{t-1} W_hh^T + b_hh), out = h_T W_fc^T + b_fc
// B=8192, T=784, I=1, H=30 (pad 32), C=10. fp32.
//
// R6 = R5 (fmac_dpp broadcast-fused MACs) with the weight-residency fix done
// RIGHT. R5 post-mortem: VGPR_Count stayed 44 => the 64 per-lane weight
// floats were STILL reloaded in-loop. Root cause, two halves:
//   (a) the R5 pins were non-volatile asm => pure instruction => LLVM may
//       sink load+pin into the loop (remat-style pressure reduction);
//   (b) __launch_bounds__(256,2) sets only a MIN waves/EU; the backend's
//       occupancy heuristic still targets high occupancy and sheds register
//       pressure down to 44 VGPRs.
// Fix: amdgpu_waves_per_eu(2,2) pins the occupancy target to exactly what we
// launch (2 waves/SIMD -> 256-VGPR budget), and the pins are asm VOLATILE
// (cannot be sunk/duplicated -- execution count is observable).
// Gate for this round: VGPR_Count must jump to >=100, else theory failed.
//
// Floor once resident: 60 fmac_dpp (120clk) + tanh (~45clk) + misc ~= 175
// clk/wave-step, 2 waves/SIMD -> ~350 clk/SIMD-step -> ~115 us.

#define BB 8192
#define TT 784
#define HH 30
#define CC 10
#define NB 16      // batches per 256-thread block (4 per wave)
#define LSTR 36    // LDS row stride (floats) for the final FC exchange

// acc += w * broadcast(h from lane k of the 16-lane DPP row)
#define FMAC_BC(acc, h, w, k) \
    asm volatile("v_fmac_f32_dpp %0, %1, %2 row_newbcast:" #k \
                 " row_mask:0xf bank_mask:0xf" \
                 : "+v"(acc) : "v"(h), "v"(w))

// dst = w * broadcast(h from lane k)   (chain head, saves the zero-init mov)
#define MUL_BC(dst, h, w, k) \
    asm volatile("v_mul_f32_dpp %0, %1, %2 row_newbcast:" #k \
                 " row_mask:0xf bank_mask:0xf" \
                 : "=v"(dst) : "v"(h), "v"(w))

#define STEP4(k) \
    FMAC_BC(a0,  h0, w0c[2*(k)],   k); \
    FMAC_BC(a0b, h1, w0c[2*(k)+1], k); \
    FMAC_BC(a1,  h0, w1c[2*(k)],   k); \
    FMAC_BC(a1b, h1, w1c[2*(k)+1], k);

__global__ __launch_bounds__(256)
__attribute__((amdgpu_waves_per_eu(2, 2)))
void rnn_scan_kernel(const float* __restrict__ x,
                     const float* __restrict__ W_ih,
                     const float* __restrict__ W_hh,
                     const float* __restrict__ b_ih,
                     const float* __restrict__ b_hh,
                     const float* __restrict__ W_fc,
                     const float* __restrict__ b_fc,
                     float* __restrict__ out) {
    __shared__ float hbuf[NB * LSTR];

    const int tid = threadIdx.x;
    const int bl  = tid >> 4;          // local batch 0..15 (4 per wave)
    const int r   = tid & 15;          // lane within the 16-lane DPP row
    const int i0  = r * 2;             // owned rows i0, i0+1
    const int b   = blockIdx.x * NB + bl;

    // --- per-thread weights: rows i0, i0+1, zero-padded to 32 cols ---
    float w0c[32], w1c[32];
    const bool v0 = (i0 < HH), v1 = (i0 + 1 < HH);
#pragma unroll
    for (int j = 0; j < 32; ++j) {
        w0c[j] = (v0 && j < HH) ? W_hh[i0 * HH + j] : 0.0f;
        w1c[j] = (v1 && j < HH) ? W_hh[(i0 + 1) * HH + j] : 0.0f;
    }
    float bias0 = v0 ? (b_ih[i0] + b_hh[i0]) : 0.0f;
    float bias1 = v1 ? (b_ih[i0 + 1] + b_hh[i0 + 1]) : 0.0f;
    float wih0  = v0 ? W_ih[i0] : 0.0f;
    float wih1  = v1 ? W_ih[i0 + 1] : 0.0f;

    // VOLATILE pins: cannot be deleted, duplicated, or sunk into the loop
    // (execution count of a volatile asm is observable). Defs stay here,
    // values stay live in VGPRs across the whole scan.
#pragma unroll
    for (int j = 0; j < 32; ++j) {
        asm volatile("" : "+v"(w0c[j]));
        asm volatile("" : "+v"(w1c[j]));
    }
    asm volatile("" : "+v"(bias0));
    asm volatile("" : "+v"(bias1));
    asm volatile("" : "+v"(wih0));
    asm volatile("" : "+v"(wih1));

    // h lives entirely in registers: lane r holds h[2r], h[2r+1].
    // invalid rows (r=15): acc==0 -> h = 1 - 2*rcp(2) == 0 exactly.
    float h0 = 0.0f, h1 = 0.0f;

    const float* xb = x + (size_t)b * TT;
    float4 xq = *(const float4*)(xb);

    for (int q = 0; q < TT / 4; ++q) {
        float4 nxt = (q + 1 < TT / 4) ? *(const float4*)(xb + (q + 1) * 4)
                                      : make_float4(0.f, 0.f, 0.f, 0.f);
#pragma unroll
        for (int u = 0; u < 4; ++u) {
            const float xt = (u == 0) ? xq.x : (u == 1) ? xq.y
                           : (u == 2) ? xq.z : xq.w;
            float a0 = fmaf(xt, wih0, bias0);
            float a1 = fmaf(xt, wih1, bias1);
            float a0b, a1b;
            // cover VALU-write(h0/h1) -> DPP-read hazard (2 wait states)
            asm volatile("s_nop 1");
            // k=0 group: b-chains start with MUL (no zero-init needed)
            FMAC_BC(a0,  h0, w0c[0], 0);
            MUL_BC (a0b, h1, w0c[1], 0);
            FMAC_BC(a1,  h0, w1c[0], 0);
            MUL_BC (a1b, h1, w1c[1], 0);
            STEP4( 1) STEP4( 2) STEP4( 3) STEP4( 4) STEP4( 5)
            STEP4( 6) STEP4( 7) STEP4( 8) STEP4( 9) STEP4(10)
            STEP4(11) STEP4(12) STEP4(13) STEP4(14)
            // k=15 dropped: cols 30,31 have w==0 and h==0 (structural zeros)
            const float acc0 = a0 + a0b;
            const float acc1 = a1 + a1b;
            // tanh(a) = 1 - 2/(e^{2a}+1)   (identical numerics to R2..R5)
            h0 = 1.0f - 2.0f * __builtin_amdgcn_rcpf(__expf(2.0f * acc0) + 1.0f);
            h1 = 1.0f - 2.0f * __builtin_amdgcn_rcpf(__expf(2.0f * acc1) + 1.0f);
        }
        xq = nxt;
    }

    // --- FC head: park final h in LDS once; threads r<10 each do one output.
    float* hp = &hbuf[bl * LSTR];
    *(float2*)&hp[i0] = make_float2(h0, h1);
    __builtin_amdgcn_wave_barrier();

    if (r < CC) {
        const int c = r;
        float acc = b_fc[c];
#pragma unroll
        for (int j = 0; j < HH; ++j)
            acc += W_fc[c * HH + j] * hp[j];
        out[(size_t)b * CC + c] = acc;
    }
}

extern "C" void kernel_launch(void* const* d_in, const int* in_sizes, int n_in,
                              void* d_out, int out_size, void* d_ws, size_t ws_size,
                              hipStream_t stream) {
    const float* x    = (const float*)d_in[0];
    const float* W_ih = (const float*)d_in[1];
    const float* W_hh = (const float*)d_in[2];
    const float* b_ih = (const float*)d_in[3];
    const float* b_hh = (const float*)d_in[4];
    const float* W_fc = (const float*)d_in[5];
    const float* b_fc = (const float*)d_in[6];

    hipLaunchKernelGGL(rnn_scan_kernel,
                       dim3(BB / NB), dim3(NB * 16), 0, stream,
                       x, W_ih, W_hh, b_ih, b_hh, W_fc, b_fc,
                       (float*)d_out);
}